// Round 2
// baseline (462.507 us; speedup 1.0000x reference)
//
#include <hip/hip_runtime.h>

// Masking: zero the k smallest mask_weights positions in weights (exact,
// tie-safe via composite key (order_u32(mask)<<32)|idx == jax top_k order).
//
// 3 dispatches:
//   hist1    : 256-bin (top-8 bits) histogram, per-thread LDS byte counters,
//              zero atomics in the hot loop (bank-uniform 2-way layout).
//   pass2    : prologue rescans hist -> b1; streams mask+weights -> out,
//              captures bin==b1 candidates (wave-aggregated atomics).
//   finalize : single block; 2048-bin refine on candidates, exact rank
//              select on composite keys, fixup writes, then zeroes globals
//              for the next call (device globals persist across launches).

typedef unsigned int u32;
typedef unsigned long long u64;

#define NB1 256
#define NB2 2048
#define CAP1 (1u << 20)
#define CAP2 2048u

__device__ u32 g_hist1[NB1];   // zero at module load; finalize re-zeroes each call
__device__ u32 g_count1;
__device__ u32 g_cand_u[CAP1];
__device__ u32 g_cand_i[CAP1];

static __device__ __forceinline__ u32 xf(u32 b) {
  // monotonic float->uint (ascending float order == ascending unsigned order)
  return b ^ ((u32)((int)b >> 31) | 0x80000000u);
}
static __device__ __forceinline__ u32 sb(u32 v) {  // sum of 4 bytes
  return (v & 0xFFu) + ((v >> 8) & 0xFFu) + ((v >> 16) & 0xFFu) + (v >> 24);
}
static __device__ __forceinline__ long long calc_k(int mpv, long long n) {
  long long k = (n * (long long)(100 - mpv)) / 100;  // matches int((1-p)*n) for p=0.50
  if (k < 0) k = 0;
  if (k > n) k = n;
  return k;
}

// wave-aggregated append to candidate buffer
static __device__ __forceinline__ void capture(u32 u, u32 idx, bool pred, int lane) {
  u64 m = __ballot(pred);
  if (m == 0ull) return;
  int lead = __ffsll((unsigned long long)m) - 1;
  u32 base = 0;
  if (lane == lead) base = atomicAdd(&g_count1, (u32)__popcll(m));
  base = __shfl(base, lead);
  if (pred) {
    u32 pos = base + (u32)__popcll(m & ((1ull << lane) - 1ull));
    if (pos < CAP1) { g_cand_u[pos] = u; g_cand_i[pos] = idx; }
  }
}

__global__ __launch_bounds__(256) void hist1_kernel(const u32* __restrict__ mb,
                                                    long long n4, long long n) {
  // per-thread byte counters: byte addr = bin*256 + lane*4 + wave
  // -> dword = bin*64 + lane -> bank = lane%32: uniform 2-way alias (free),
  //    independent of bin distribution; each thread owns a unique byte.
  __shared__ unsigned char sh[NB1 * 256];  // 64 KB
  const int t = threadIdx.x;
  {
    uint4* s4 = (uint4*)sh;
#pragma unroll
    for (int i = 0; i < 16; i++) s4[i * 256 + t] = make_uint4(0u, 0u, 0u, 0u);
  }
  __syncthreads();
  unsigned char* base = sh + ((t & 63) << 2) + (t >> 6);
  const long long stride = (long long)gridDim.x * 256;
  const uint4* mb4 = (const uint4*)mb;
  for (long long i = (long long)blockIdx.x * 256 + t; i < n4; i += stride) {
    uint4 v = mb4[i];
    base[(xf(v.x) >> 24) << 8] += 1;
    base[(xf(v.y) >> 24) << 8] += 1;
    base[(xf(v.z) >> 24) << 8] += 1;
    base[(xf(v.w) >> 24) << 8] += 1;
  }
  if (blockIdx.x == 0) {  // scalar tail (n % 4)
    long long rs = n4 << 2;
    if ((long long)t < n - rs) base[(xf(mb[rs + t]) >> 24) << 8] += 1;
  }
  __syncthreads();
  // reduce: thread t sums bin-row t (256 bytes = 16 uint4, rotated)
  const uint4* row = (const uint4*)(sh + (t << 8));
  u32 s = 0;
#pragma unroll
  for (int j = 0; j < 16; j++) {
    uint4 v = row[(j + t) & 15];
    s += sb(v.x) + sb(v.y) + sb(v.z) + sb(v.w);
  }
  if (s) atomicAdd(&g_hist1[t], s);
}

__global__ __launch_bounds__(256) void pass2_kernel(const u32* __restrict__ mb,
                                                    const float* __restrict__ w,
                                                    float* __restrict__ out,
                                                    const int* __restrict__ mp,
                                                    long long n4, long long n) {
  __shared__ u32 scan[256];
  __shared__ int s_b1;
  const int t = threadIdx.x;
  if (t == 0) s_b1 = -1;
  const long long k = calc_k(*mp, n);
  // prologue: inclusive scan of g_hist1 -> b1 (bin containing rank k)
  u32 c = g_hist1[t];
  u32 x = c;
  scan[t] = x;
  __syncthreads();
  for (int off = 1; off < 256; off <<= 1) {
    u32 v = (t >= off) ? scan[t - off] : 0u;
    __syncthreads();
    x += v;
    scan[t] = x;
    __syncthreads();
  }
  if (k > 0 && (long long)(x - c) < k && k <= (long long)x) s_b1 = t;
  __syncthreads();
  const int b1 = s_b1;  // -1 => k==0: nothing zeroed, no candidates
  const int lane = t & 63;
  const long long stride = (long long)gridDim.x * 256;
  const uint4* mb4 = (const uint4*)mb;
  const float4* w4 = (const float4*)w;
  float4* o4 = (float4*)out;
  for (long long i = (long long)blockIdx.x * 256 + t; i < n4; i += stride) {
    uint4 mv = mb4[i];
    float4 wv = w4[i];
    u32 u0 = xf(mv.x), u1 = xf(mv.y), u2 = xf(mv.z), u3 = xf(mv.w);
    int c0 = (int)(u0 >> 24), c1 = (int)(u1 >> 24), c2 = (int)(u2 >> 24), c3 = (int)(u3 >> 24);
    float4 o;
    o.x = (c0 < b1) ? 0.0f : wv.x;
    o.y = (c1 < b1) ? 0.0f : wv.y;
    o.z = (c2 < b1) ? 0.0f : wv.z;
    o.w = (c3 < b1) ? 0.0f : wv.w;
    o4[i] = o;
    u32 bidx = (u32)(i << 2);
    capture(u0, bidx + 0u, c0 == b1, lane);
    capture(u1, bidx + 1u, c1 == b1, lane);
    capture(u2, bidx + 2u, c2 == b1, lane);
    capture(u3, bidx + 3u, c3 == b1, lane);
  }
  if (blockIdx.x == 0) {  // scalar tail
    long long rs = n4 << 2;
    long long i = rs + t;
    bool act = i < n;
    u32 u = 0;
    bool pred = false;
    if (act) {
      u = xf(mb[i]);
      int b = (int)(u >> 24);
      out[i] = (b < b1) ? 0.0f : w[i];
      pred = (b == b1);
    }
    capture(u, (u32)i, pred, lane);
  }
}

__global__ __launch_bounds__(256) void finalize_kernel(const int* __restrict__ mp,
                                                       long long n,
                                                       float* __restrict__ out) {
  __shared__ u32 h2[NB2];
  __shared__ u64 k2[CAP2];
  __shared__ u32 scan[256];
  __shared__ int s_b1, s_b2;
  __shared__ u32 s_rem1, s_rem2, s_c2;
  __shared__ u64 s_kstar;
  const int t = threadIdx.x;
  if (t == 0) { s_b1 = -1; s_b2 = 0; s_rem1 = 0; s_rem2 = 0; s_c2 = 0; s_kstar = 0ull; }
  const long long k = calc_k(*mp, n);
  // level-1: recompute b1 + rem1 (rank within bin b1)
  u32 c = g_hist1[t];
  u32 x = c;
  scan[t] = x;
  __syncthreads();
  for (int off = 1; off < 256; off <<= 1) {
    u32 v = (t >= off) ? scan[t - off] : 0u;
    __syncthreads();
    x += v;
    scan[t] = x;
    __syncthreads();
  }
  if (k > 0 && (long long)(x - c) < k && k <= (long long)x) {
    s_b1 = t;
    s_rem1 = (u32)(k - (long long)(x - c));
  }
  __syncthreads();
  const int b1 = s_b1;
  if (b1 >= 0) {
    const u32 C = min(g_count1, CAP1);
    // level-2: histogram candidates by next 11 bits (u bits 23..13)
    for (int i = t; i < NB2; i += 256) h2[i] = 0u;
    __syncthreads();
    for (u32 i = (u32)t; i < C; i += 256) atomicAdd(&h2[(g_cand_u[i] >> 13) & (NB2 - 1u)], 1u);
    __syncthreads();
    u32 loc[8];
    u32 s = 0;
#pragma unroll
    for (int j = 0; j < 8; j++) { loc[j] = h2[t * 8 + j]; s += loc[j]; }
    u32 y = s;
    scan[t] = y;
    __syncthreads();
    for (int off = 1; off < 256; off <<= 1) {
      u32 v = (t >= off) ? scan[t - off] : 0u;
      __syncthreads();
      y += v;
      scan[t] = y;
      __syncthreads();
    }
    const u32 rem1 = s_rem1;
    u32 excl2 = y - s;
    if (excl2 < rem1 && rem1 <= y) {
      u32 cum = excl2;
#pragma unroll
      for (int j = 0; j < 8; j++) {
        if (cum + loc[j] >= rem1) { s_b2 = t * 8 + j; s_rem2 = rem1 - cum; break; }
        cum += loc[j];
      }
    }
    __syncthreads();
    const u32 b2 = (u32)s_b2;
    // collect sub-bin b2 candidates (expected C/2048 ~ few)
    for (u32 i = (u32)t; i < C; i += 256) {
      u32 u = g_cand_u[i];
      if (((u >> 13) & (NB2 - 1u)) == b2) {
        u32 slot = atomicAdd(&s_c2, 1u);
        if (slot < CAP2) k2[slot] = ((u64)u << 32) | (u64)g_cand_i[i];
      }
    }
    __syncthreads();
    const u32 C2 = min(s_c2, CAP2);
    const u32 rem2 = s_rem2;
    // exact rank select on unique composite keys
    for (u32 i = (u32)t; i < C2; i += 256) {
      u64 key = k2[i];
      u32 cnt = 0;
      for (u32 j = 0; j < C2; j++) cnt += (k2[j] < key) ? 1u : 0u;
      if (cnt + 1u == rem2) s_kstar = key + 1ull;  // exclusive threshold
    }
    __syncthreads();
    const u64 kstar = s_kstar;
    // fixup: zero candidates below threshold
    for (u32 i = (u32)t; i < C; i += 256) {
      u32 idx = g_cand_i[i];
      u64 key = ((u64)g_cand_u[i] << 32) | (u64)idx;
      if (key < kstar) out[idx] = 0.0f;
    }
  }
  __syncthreads();
  // reset persistent globals for the next call (module-load state is zero)
  g_hist1[t] = 0u;  // NB1 == blockDim == 256
  if (t == 0) g_count1 = 0u;
}

extern "C" void kernel_launch(void* const* d_in, const int* in_sizes, int n_in,
                              void* d_out, int out_size, void* d_ws, size_t ws_size,
                              hipStream_t stream) {
  const float* w  = (const float*)d_in[0];
  const u32*   mb = (const u32*)d_in[1];
  const int*   mp = (const int*)d_in[2];
  float* out = (float*)d_out;
  const long long n  = (long long)in_sizes[0];
  const long long n4 = n >> 2;

  // hist1 grid: keep per-thread elements <= 128 so byte counters can't overflow
  long long hb = (n4 + 8191) / 8192;
  if (hb < 1) hb = 1;
  if (hb > 16384) hb = 16384;
  long long pb = (n4 + 255) / 256;
  if (pb < 1) pb = 1;
  if (pb > 4096) pb = 4096;

  hist1_kernel<<<(int)hb, 256, 0, stream>>>(mb, n4, n);
  pass2_kernel<<<(int)pb, 256, 0, stream>>>(mb, w, out, mp, n4, n);
  finalize_kernel<<<1, 256, 0, stream>>>(mp, n, out);
}